// Round 7
// baseline (27.382 us; speedup 1.0000x reference)
//
#include <hip/hip_runtime.h>
#include <math.h>

// Problem constants (from reference setup_inputs): B=2, S=1024, F=512, N=128.
#define F 512
#define N 128
#define G 256                 // density-table points per feature (LDS)

constexpr float PROB_THRESHOLD = 0.3f;
constexpr float MARGIN         = 1e-4f;   // certified interp error ~2.4e-5, ~4x headroom
constexpr float INV_SQRT_2PI   = 0.3989422804014327f;
// exp(-0.5*z^2) = exp2(-(z*SCALE_C)^2), SCALE_C = sqrt(0.5*log2(e))
constexpr float SCALE_C = 0.8493218002880191f;
// 128^(-0.2)  (Scott's rule factor)
constexpr float FACTOR  = 0.37892914162759955f;
constexpr float PAD_T   = 8.0f;           // grid padding in t-units (exp2(-64)~0)

// ---------------------------------------------------------------------------
// Single kernel, no workspace. One block per FEATURE (256 threads, 4 waves);
// block b owns feature f = swizzle(b) and all 2048 rows of it.
//
// Phase 1: stats — R6-validated reduction tree (butterfly + 4 LDS partials).
// Phase 2: density table (G=256 points) built into LDS; thread g owns point
//          g: 128 exps reading the kde column from LDS. Formulas identical
//          to R6's kde_prep (absmax=0).
// Phase 3: apply — 8 rows per thread; cubic Lagrange interp from the LDS
//          table (identical arithmetic to R6's kde_apply); ambiguous band
//          |dens-0.3|<MARGIN recomputed exactly with R3's validated chain,
//          now reading kde values from LDS (bit-identical floats).
//
// x/out accesses are 2KB-strided (feature-column walk). The block swizzle
// f=(bid&7)*64+(bid>>3) groups features [64k,64k+64) on XCD k (assuming
// round-robin dispatch), so each 64B line of x/out is read+written entirely
// within one XCD's L2: HBM traffic stays ~= x+out = 8MB. Perf-only heuristic.
// ---------------------------------------------------------------------------
__global__ __launch_bounds__(256) void kde_mask_one(const float* __restrict__ x,
                                                    const float* __restrict__ kde,
                                                    const float* __restrict__ repl,
                                                    float* __restrict__ out,
                                                    int rows) {
    const int bid  = blockIdx.x;
    const int f    = ((bid & 7) << 6) | (bid >> 3);  // XCD-locality swizzle
    const int tid  = threadIdx.x;
    const int lane = tid & 63;
    const int wv   = tid >> 6;

    __shared__ float vbuf[N];       // raw kde column (exact loaded floats)
    __shared__ float table[G];      // density table
    __shared__ float redS[4], redSS[4], redMN[4], redMX[4];

    // ---- Phase 1: stats (identical tree to validated R6 kde_prep) ----
    float v = 0.f, vmn = INFINITY, vmx = -INFINITY;
    if (tid < N) {
        v = kde[tid * F + f];
        vbuf[tid] = v;
        vmn = v;
        vmx = v;
    }
    float s  = v;
    float ss = v * v;
#pragma unroll
    for (int off = 32; off >= 1; off >>= 1) {
        s   += __shfl_xor(s, off);
        ss  += __shfl_xor(ss, off);
        vmn  = fminf(vmn, __shfl_xor(vmn, off));
        vmx  = fmaxf(vmx, __shfl_xor(vmx, off));
    }
    if (lane == 0) { redS[wv] = s; redSS[wv] = ss; redMN[wv] = vmn; redMX[wv] = vmx; }
    __syncthreads();

    const float S  = (redS[0] + redS[1]) + (redS[2] + redS[3]);
    const float SS = (redSS[0] + redSS[1]) + (redSS[2] + redSS[3]);
    const float MN = fminf(fminf(redMN[0], redMN[1]), fminf(redMN[2], redMN[3]));
    const float MX = fmaxf(fmaxf(redMX[0], redMX[1]), fmaxf(redMX[2], redMX[3]));

    const float mean  = S * (1.0f / N);
    const float var   = (SS - S * mean) * (1.0f / (N - 1));
    const float bw    = FACTOR * sqrtf(var);
    const float scale = SCALE_C / bw;
    const float coef  = INV_SQRT_2PI / bw;
    const float t0    = MN * scale - PAD_T;
    const float t1    = MX * scale + PAD_T;
    const float invht = (float)(G - 1) / (t1 - t0);
    const float ht    = 1.0f / invht;

    // ---- Phase 2: table build (identical formulas to validated R6) ----
    const float tg = fmaf((float)tid, ht, t0);
    float acc = 0.f;
#pragma unroll 8
    for (int n = 0; n < N; ++n) {
        const float a = vbuf[n] * scale;
        const float z = tg - a;
        acc += __builtin_amdgcn_exp2f(-(z * z));
    }
    table[tid] = (acc * (1.0f / N)) * coef;
    __syncthreads();

    // ---- Phase 3: apply (interp arithmetic identical to validated R6) ----
    const float sx = scale * invht;   // same products as R6's const4 packing
    const float sy = -t0 * invht;
    const float rv = repl[f];

    for (int r0 = 0; r0 < rows; r0 += 2048) {
        float xv[8];
        int   e[8];
#pragma unroll
        for (int k = 0; k < 8; ++k) {          // issue all 8 loads up front
            const int r = r0 + (k << 8) + tid;
            e[k]  = r * F + f;
            xv[k] = (r < rows) ? x[e[k]] : 0.f;
        }
#pragma unroll
        for (int k = 0; k < 8; ++k) {
            const int r = r0 + (k << 8) + tid;
            if (r >= rows) break;
            const float u = fmaf(xv[k], sx, sy);
            float res = xv[k];
            if (u >= 1.0f && u < (float)(G - 2)) {
                const int   i    = (int)u;
                const float sfr  = u - (float)i;
                const float p0 = table[i - 1];
                const float p1 = table[i + 0];
                const float p2 = table[i + 1];
                const float p3 = table[i + 2];
                const float sm1 = sfr - 1.0f, sm2 = sfr - 2.0f, sp1 = sfr + 1.0f;
                const float w0 = -sfr * sm1 * sm2 * (1.0f / 6.0f);
                const float w1 = sp1 * sm1 * sm2 * 0.5f;
                const float w2 = -sp1 * sfr * sm2 * 0.5f;
                const float w3 = sp1 * sfr * sm1 * (1.0f / 6.0f);
                const float dens = w0 * p0 + w1 * p1 + w2 * p2 + w3 * p3;

                if (dens >= PROB_THRESHOLD + MARGIN) {
                    res = rv;
                } else if (dens >= PROB_THRESHOLD - MARGIN) {
                    // Exact recompute — bitwise R3 chain (validated absmax=0);
                    // vbuf holds the exact kde floats.
                    const float t   = xv[k] * scale;
                    const float t2a = t + t;
                    const float et  = __builtin_amdgcn_exp2f(-(t * t));
                    float acc2 = 0.f;
#pragma unroll 8
                    for (int n = 0; n < N; ++n) {
                        const float a   = vbuf[n] * scale;
                        const float na2 = -(a * a);
                        acc2 += __builtin_amdgcn_exp2f(fmaf(t2a, a, na2));
                    }
                    const float sum   = acc2 * et;
                    const float dens2 = (sum * (1.0f / N)) * coef;
                    res = (dens2 >= PROB_THRESHOLD) ? rv : xv[k];
                }
            }
            // (u out of range => nearest sample >= ~7.9 t-units => dens < 1e-18 => keep x)
            out[e[k]] = res;
        }
    }
}

extern "C" void kernel_launch(void* const* d_in, const int* in_sizes, int n_in,
                              void* d_out, int out_size, void* d_ws, size_t ws_size,
                              hipStream_t stream) {
    const float* x    = (const float*)d_in[0];
    const float* kde  = (const float*)d_in[1];
    const float* repl = (const float*)d_in[2];
    float* out        = (float*)d_out;

    const int rows = in_sizes[0] / F;  // B*S = 2048
    kde_mask_one<<<F, 256, 0, stream>>>(x, kde, repl, out, rows);
}

// Round 8
// 26.657 us; speedup vs baseline: 1.0272x; 1.0272x over previous
//
#include <hip/hip_runtime.h>
#include <math.h>

// Problem constants (from reference setup_inputs): B=2, S=1024, F=512, N=128.
#define F 512
#define N 128
#define G 256                 // density-table points per feature
#define ROWS 4                // fallback kernel rows/block

constexpr float PROB_THRESHOLD = 0.3f;
constexpr float MARGIN         = 1e-4f;   // certified interp error ~2.4e-5, ~4x headroom
constexpr float INV_SQRT_2PI   = 0.3989422804014327f;
// exp(-0.5*z^2) = exp2(-(z*SCALE_C)^2), SCALE_C = sqrt(0.5*log2(e))
constexpr float SCALE_C = 0.8493218002880191f;
// 128^(-0.2)  (Scott's rule factor)
constexpr float FACTOR  = 0.37892914162759955f;
constexpr float PAD_T   = 8.0f;           // grid padding in t-units (exp2(-64)~0)

// ---------------------------------------------------------------------------
// Kernel A: identical to validated R6 kde_prep (absmax=0). One block per
// feature; fused stats (butterfly + 4 LDS partials) + density-table build.
// ---------------------------------------------------------------------------
__global__ __launch_bounds__(G) void kde_prep(const float* __restrict__ kde,
                                              const float* __restrict__ repl,
                                              float* __restrict__ table,
                                              float4* __restrict__ const4,
                                              float* __restrict__ coefs) {
    const int f    = blockIdx.x;
    const int tid  = threadIdx.x;
    const int lane = tid & 63;
    const int wv   = tid >> 6;

    __shared__ float vbuf[N];
    __shared__ float redS[4], redSS[4], redMN[4], redMX[4];

    float v = 0.f, vmn = INFINITY, vmx = -INFINITY;
    if (tid < N) {
        v = kde[tid * F + f];
        vbuf[tid] = v;
        vmn = v;
        vmx = v;
    }
    float s  = v;
    float ss = v * v;
#pragma unroll
    for (int off = 32; off >= 1; off >>= 1) {
        s   += __shfl_xor(s, off);
        ss  += __shfl_xor(ss, off);
        vmn  = fminf(vmn, __shfl_xor(vmn, off));
        vmx  = fmaxf(vmx, __shfl_xor(vmx, off));
    }
    if (lane == 0) { redS[wv] = s; redSS[wv] = ss; redMN[wv] = vmn; redMX[wv] = vmx; }
    __syncthreads();

    const float S  = (redS[0] + redS[1]) + (redS[2] + redS[3]);
    const float SS = (redSS[0] + redSS[1]) + (redSS[2] + redSS[3]);
    const float MN = fminf(fminf(redMN[0], redMN[1]), fminf(redMN[2], redMN[3]));
    const float MX = fmaxf(fmaxf(redMX[0], redMX[1]), fmaxf(redMX[2], redMX[3]));

    const float mean  = S * (1.0f / N);
    const float var   = (SS - S * mean) * (1.0f / (N - 1));
    const float bw    = FACTOR * sqrtf(var);
    const float scale = SCALE_C / bw;
    const float coef  = INV_SQRT_2PI / bw;
    const float t0    = MN * scale - PAD_T;
    const float t1    = MX * scale + PAD_T;
    const float invht = (float)(G - 1) / (t1 - t0);
    const float ht    = 1.0f / invht;

    const float tg = fmaf((float)tid, ht, t0);
    float acc = 0.f;
#pragma unroll 8
    for (int n = 0; n < N; ++n) {
        const float a = vbuf[n] * scale;
        const float z = tg - a;
        acc += __builtin_amdgcn_exp2f(-(z * z));
    }
    table[f * G + tid] = (acc * (1.0f / N)) * coef;

    if (tid == 0) {
        const4[f] = make_float4(scale * invht, -t0 * invht, repl[f], scale);
        coefs[f]  = coef;
    }
}

// ---------------------------------------------------------------------------
// Kernel B: apply, float4-vectorized — 4 consecutive elements (= 4 consecutive
// features) per thread. 1024 blocks x 256 threads. Per-element arithmetic is
// bit-identical to validated R6 kde_apply: same interp weights, same refine
// chain, same decision thresholds.
// ---------------------------------------------------------------------------
__global__ __launch_bounds__(256) void kde_apply4(const float4* __restrict__ x4,
                                                  const float* __restrict__ kde,
                                                  const float* __restrict__ table,
                                                  const float4* __restrict__ const4,
                                                  const float* __restrict__ coefs,
                                                  float4* __restrict__ out4) {
    const int g  = blockIdx.x * 256 + threadIdx.x;   // float4 index
    const int e0 = g << 2;
    const int f0 = e0 & (F - 1);                     // 4 consecutive features

    const float4 xv = x4[g];
    float xin[4] = {xv.x, xv.y, xv.z, xv.w};
    float res[4];

#pragma unroll
    for (int j = 0; j < 4; ++j) {
        const int   f = f0 + j;
        const float xj = xin[j];
        const float4 c = const4[f];          // {scale*invht, -t0*invht, rv, scale}
        const float u  = fmaf(xj, c.x, c.y);

        float r = xj;
        if (u >= 1.0f && u < (float)(G - 2)) {
            const int   i    = (int)u;
            const float sfr  = u - (float)i;
            const int   base = f * G + i - 1;
            const float p0 = table[base + 0];
            const float p1 = table[base + 1];
            const float p2 = table[base + 2];
            const float p3 = table[base + 3];
            const float sm1 = sfr - 1.0f, sm2 = sfr - 2.0f, sp1 = sfr + 1.0f;
            const float w0 = -sfr * sm1 * sm2 * (1.0f / 6.0f);
            const float w1 = sp1 * sm1 * sm2 * 0.5f;
            const float w2 = -sp1 * sfr * sm2 * 0.5f;
            const float w3 = sp1 * sfr * sm1 * (1.0f / 6.0f);
            const float dens = w0 * p0 + w1 * p1 + w2 * p2 + w3 * p3;

            if (dens >= PROB_THRESHOLD + MARGIN) {
                r = c.z;
            } else if (dens >= PROB_THRESHOLD - MARGIN) {
                // Exact recompute — bitwise R3/R6 chain (validated absmax=0).
                const float scale = c.w;
                const float coef  = coefs[f];
                const float t     = xj * scale;
                const float t2    = t + t;
                const float et    = __builtin_amdgcn_exp2f(-(t * t));
                float acc = 0.f;
#pragma unroll 8
                for (int n = 0; n < N; ++n) {
                    const float a   = kde[n * F + f] * scale;
                    const float na2 = -(a * a);
                    acc += __builtin_amdgcn_exp2f(fmaf(t2, a, na2));
                }
                const float sum   = acc * et;
                const float dens2 = (sum * (1.0f / N)) * coef;
                r = (dens2 >= PROB_THRESHOLD) ? c.z : xj;
            }
        }
        // (u out of range => nearest sample >= ~7.9 t-units => dens < 1e-18 => keep x)
        res[j] = r;
    }

    out4[g] = make_float4(res[0], res[1], res[2], res[3]);
}

// ---------------------------------------------------------------------------
// Fallback (ws too small): R4's validated fused direct kernel, unchanged.
// ---------------------------------------------------------------------------
__global__ __launch_bounds__(512) void kde_mask_fused(const float* __restrict__ x,
                                                      const float* __restrict__ kde,
                                                      const float* __restrict__ repl,
                                                      float* __restrict__ out) {
    const int f  = threadIdx.x;
    const int r0 = blockIdx.x * ROWS;

    float s = 0.f, ss = 0.f;
#pragma unroll 8
    for (int n = 0; n < N; ++n) {
        const float v = kde[n * F + f];
        s += v;
        ss = fmaf(v, v, ss);
    }
    const float mean  = s * (1.0f / N);
    const float var   = (ss - s * mean) * (1.0f / (N - 1));
    const float bw    = FACTOR * sqrtf(var);
    const float scale = SCALE_C / bw;
    const float coef  = INV_SQRT_2PI / bw;

    float xv[ROWS], t2[ROWS], et[ROWS], acc[ROWS];
#pragma unroll
    for (int k = 0; k < ROWS; ++k) {
        xv[k]  = x[(r0 + k) * F + f];
        const float t = xv[k] * scale;
        t2[k]  = t + t;
        et[k]  = __builtin_amdgcn_exp2f(-(t * t));
        acc[k] = 0.f;
    }
#pragma unroll 8
    for (int n = 0; n < N; ++n) {
        const float v   = kde[n * F + f];
        const float a   = v * scale;
        const float na2 = -(a * a);
#pragma unroll
        for (int k = 0; k < ROWS; ++k) {
            acc[k] += __builtin_amdgcn_exp2f(fmaf(t2[k], a, na2));
        }
    }
    const float rv = repl[f];
#pragma unroll
    for (int k = 0; k < ROWS; ++k) {
        const float sum  = acc[k] * et[k];
        const float dens = (sum * (1.0f / N)) * coef;
        out[(r0 + k) * F + f] = (dens >= PROB_THRESHOLD) ? rv : xv[k];
    }
}

extern "C" void kernel_launch(void* const* d_in, const int* in_sizes, int n_in,
                              void* d_out, int out_size, void* d_ws, size_t ws_size,
                              hipStream_t stream) {
    const float* x    = (const float*)d_in[0];
    const float* kde  = (const float*)d_in[1];
    const float* repl = (const float*)d_in[2];
    float* out        = (float*)d_out;

    const int rows  = in_sizes[0] / F;   // B*S = 2048
    const int total = in_sizes[0];       // 1,048,576

    const size_t need = (size_t)(F * G) * sizeof(float)   // table
                      + (size_t)F * sizeof(float4)        // const4
                      + (size_t)F * sizeof(float);        // coefs
    if (ws_size >= need) {
        float*  table  = (float*)d_ws;
        float4* const4 = (float4*)(table + (size_t)F * G);  // 512KB offset, 16B-aligned
        float*  coefs  = (float*)(const4 + F);
        kde_prep<<<F, G, 0, stream>>>(kde, repl, table, const4, coefs);
        kde_apply4<<<total / 4 / 256, 256, 0, stream>>>((const float4*)x, kde, table,
                                                        const4, coefs, (float4*)out);
    } else {
        kde_mask_fused<<<rows / ROWS, 512, 0, stream>>>(x, kde, repl, out);
    }
}

// Round 9
// 23.763 us; speedup vs baseline: 1.1523x; 1.1218x over previous
//
#include <hip/hip_runtime.h>
#include <math.h>

// Problem constants (from reference setup_inputs): B=2, S=1024, F=512, N=128.
#define F 512
#define N 128
#define G 256                 // density-table points per feature
#define ROWS 4                // fallback kernel rows/block

constexpr float PROB_THRESHOLD = 0.3f;
constexpr float MARGIN         = 1e-4f;   // certified interp error bound ~2e-5, 5x headroom
constexpr float INV_SQRT_2PI   = 0.3989422804014327f;
// exp(-0.5*z^2) = exp2(-(z*SCALE_C)^2), SCALE_C = sqrt(0.5*log2(e))
constexpr float SCALE_C = 0.8493218002880191f;
// 128^(-0.2)  (Scott's rule factor)
constexpr float FACTOR  = 0.37892914162759955f;
constexpr float PAD_T   = 8.0f;           // grid padding in t-units (exp2(-64)~0)

// ---------------------------------------------------------------------------
// Kernel A: one block per feature (512 blocks x 256 threads).
// Fuses stats (block reduction, one-pass var validated in R4) + density-table
// build (thread g computes grid point g; kde column cached in LDS).
// Also packs per-feature apply constants: const4 = {scale*invht, -t0*invht,
// repl, scale}; coefs[f] for the rare refine path.
// ---------------------------------------------------------------------------
__global__ __launch_bounds__(G) void kde_prep(const float* __restrict__ kde,
                                              const float* __restrict__ repl,
                                              float* __restrict__ table,
                                              float4* __restrict__ const4,
                                              float* __restrict__ coefs) {
    const int f    = blockIdx.x;
    const int tid  = threadIdx.x;
    const int lane = tid & 63;
    const int wv   = tid >> 6;

    __shared__ float vbuf[N];
    __shared__ float redS[4], redSS[4], redMN[4], redMX[4];

    float v = 0.f, vmn = INFINITY, vmx = -INFINITY;
    if (tid < N) {
        v = kde[tid * F + f];
        vbuf[tid] = v;
        vmn = v;
        vmx = v;
    }
    float s  = v;
    float ss = v * v;
#pragma unroll
    for (int off = 32; off >= 1; off >>= 1) {
        s   += __shfl_xor(s, off);
        ss  += __shfl_xor(ss, off);
        vmn  = fminf(vmn, __shfl_xor(vmn, off));
        vmx  = fmaxf(vmx, __shfl_xor(vmx, off));
    }
    if (lane == 0) { redS[wv] = s; redSS[wv] = ss; redMN[wv] = vmn; redMX[wv] = vmx; }
    __syncthreads();

    // Every thread recomputes the (identical) scalars from the 4 partials.
    const float S  = (redS[0] + redS[1]) + (redS[2] + redS[3]);
    const float SS = (redSS[0] + redSS[1]) + (redSS[2] + redSS[3]);
    const float MN = fminf(fminf(redMN[0], redMN[1]), fminf(redMN[2], redMN[3]));
    const float MX = fmaxf(fmaxf(redMX[0], redMX[1]), fmaxf(redMX[2], redMX[3]));

    const float mean  = S * (1.0f / N);
    const float var   = (SS - S * mean) * (1.0f / (N - 1));
    const float bw    = FACTOR * sqrtf(var);
    const float scale = SCALE_C / bw;
    const float coef  = INV_SQRT_2PI / bw;
    const float t0    = MN * scale - PAD_T;
    const float t1    = MX * scale + PAD_T;
    const float invht = (float)(G - 1) / (t1 - t0);
    const float ht    = 1.0f / invht;

    // Build: thread tid owns grid point tid (128 exps, LDS-broadcast reads).
    const float tg = fmaf((float)tid, ht, t0);
    float acc = 0.f;
#pragma unroll 8
    for (int n = 0; n < N; ++n) {
        const float a = vbuf[n] * scale;
        const float z = tg - a;
        acc += __builtin_amdgcn_exp2f(-(z * z));
    }
    table[f * G + tid] = (acc * (1.0f / N)) * coef;

    if (tid == 0) {
        const4[f] = make_float4(scale * invht, -t0 * invht, repl[f], scale);
        coefs[f]  = coef;
    }
}

// ---------------------------------------------------------------------------
// Kernel B: apply. One thread per element; single float4 constant load;
// cubic Lagrange interp (identical arithmetic to validated R5); ambiguous
// band recomputed exactly with R3 arithmetic — now UNROLLED so the 128 kde
// loads pipeline instead of serializing on latency.
// ---------------------------------------------------------------------------
__global__ __launch_bounds__(256) void kde_apply(const float* __restrict__ x,
                                                 const float* __restrict__ kde,
                                                 const float* __restrict__ table,
                                                 const float4* __restrict__ const4,
                                                 const float* __restrict__ coefs,
                                                 float* __restrict__ out) {
    const int e = blockIdx.x * 256 + threadIdx.x;
    const int f = e & (F - 1);

    const float  xv = x[e];
    const float4 c  = const4[f];            // {scale*invht, -t0*invht, rv, scale}
    const float  u  = fmaf(xv, c.x, c.y);

    float res = xv;
    if (u >= 1.0f && u < (float)(G - 2)) {
        const int   i    = (int)u;
        const float sfr  = u - (float)i;
        const int   base = f * G + i - 1;
        const float p0 = table[base + 0];
        const float p1 = table[base + 1];
        const float p2 = table[base + 2];
        const float p3 = table[base + 3];
        const float sm1 = sfr - 1.0f, sm2 = sfr - 2.0f, sp1 = sfr + 1.0f;
        const float w0 = -sfr * sm1 * sm2 * (1.0f / 6.0f);
        const float w1 = sp1 * sm1 * sm2 * 0.5f;
        const float w2 = -sp1 * sfr * sm2 * 0.5f;
        const float w3 = sp1 * sfr * sm1 * (1.0f / 6.0f);
        const float dens = w0 * p0 + w1 * p1 + w2 * p2 + w3 * p3;

        if (dens >= PROB_THRESHOLD + MARGIN) {
            res = c.z;
        } else if (dens >= PROB_THRESHOLD - MARGIN) {
            // Exact recompute — bitwise R3 arithmetic (validated absmax=0).
            const float scale = c.w;
            const float coef  = coefs[f];
            const float t     = xv * scale;
            const float t2    = t + t;
            const float et    = __builtin_amdgcn_exp2f(-(t * t));
            float acc = 0.f;
#pragma unroll 8
            for (int n = 0; n < N; ++n) {
                const float a   = kde[n * F + f] * scale;
                const float na2 = -(a * a);
                acc += __builtin_amdgcn_exp2f(fmaf(t2, a, na2));
            }
            const float sum   = acc * et;
            const float dens2 = (sum * (1.0f / N)) * coef;
            res = (dens2 >= PROB_THRESHOLD) ? c.z : xv;
        }
    }
    // (u out of range => nearest sample >= ~7.9 t-units => dens < 1e-18 => keep x)

    out[e] = res;
}

// ---------------------------------------------------------------------------
// Fallback (ws too small): R4's validated fused direct kernel, unchanged.
// ---------------------------------------------------------------------------
__global__ __launch_bounds__(512) void kde_mask_fused(const float* __restrict__ x,
                                                      const float* __restrict__ kde,
                                                      const float* __restrict__ repl,
                                                      float* __restrict__ out) {
    const int f  = threadIdx.x;
    const int r0 = blockIdx.x * ROWS;

    float s = 0.f, ss = 0.f;
#pragma unroll 8
    for (int n = 0; n < N; ++n) {
        const float v = kde[n * F + f];
        s += v;
        ss = fmaf(v, v, ss);
    }
    const float mean  = s * (1.0f / N);
    const float var   = (ss - s * mean) * (1.0f / (N - 1));
    const float bw    = FACTOR * sqrtf(var);
    const float scale = SCALE_C / bw;
    const float coef  = INV_SQRT_2PI / bw;

    float xv[ROWS], t2[ROWS], et[ROWS], acc[ROWS];
#pragma unroll
    for (int k = 0; k < ROWS; ++k) {
        xv[k]  = x[(r0 + k) * F + f];
        const float t = xv[k] * scale;
        t2[k]  = t + t;
        et[k]  = __builtin_amdgcn_exp2f(-(t * t));
        acc[k] = 0.f;
    }
#pragma unroll 8
    for (int n = 0; n < N; ++n) {
        const float v   = kde[n * F + f];
        const float a   = v * scale;
        const float na2 = -(a * a);
#pragma unroll
        for (int k = 0; k < ROWS; ++k) {
            acc[k] += __builtin_amdgcn_exp2f(fmaf(t2[k], a, na2));
        }
    }
    const float rv = repl[f];
#pragma unroll
    for (int k = 0; k < ROWS; ++k) {
        const float sum  = acc[k] * et[k];
        const float dens = (sum * (1.0f / N)) * coef;
        out[(r0 + k) * F + f] = (dens >= PROB_THRESHOLD) ? rv : xv[k];
    }
}

extern "C" void kernel_launch(void* const* d_in, const int* in_sizes, int n_in,
                              void* d_out, int out_size, void* d_ws, size_t ws_size,
                              hipStream_t stream) {
    const float* x    = (const float*)d_in[0];
    const float* kde  = (const float*)d_in[1];
    const float* repl = (const float*)d_in[2];
    float* out        = (float*)d_out;

    const int rows  = in_sizes[0] / F;   // B*S = 2048
    const int total = in_sizes[0];       // 1,048,576

    const size_t need = (size_t)(F * G) * sizeof(float)   // table
                      + (size_t)F * sizeof(float4)        // const4
                      + (size_t)F * sizeof(float);        // coefs
    if (ws_size >= need) {
        float*  table  = (float*)d_ws;
        float4* const4 = (float4*)(table + (size_t)F * G);  // 512KB offset, 16B-aligned
        float*  coefs  = (float*)(const4 + F);
        kde_prep<<<F, G, 0, stream>>>(kde, repl, table, const4, coefs);
        kde_apply<<<total / 256, 256, 0, stream>>>(x, kde, table, const4, coefs, out);
    } else {
        kde_mask_fused<<<rows / ROWS, 512, 0, stream>>>(x, kde, repl, out);
    }
}

// Round 10
// 17.780 us; speedup vs baseline: 1.5401x; 1.3365x over previous
//
#include <hip/hip_runtime.h>
#include <math.h>

// Problem constants (from reference setup_inputs): B=2, S=1024, F=512, N=128.
#define F 512
#define N 128
#define G 256                 // density-table points per feature
#define ROWS 4                // fallback kernel rows/block

constexpr float PROB_THRESHOLD = 0.3f;
constexpr float MARGIN         = 1e-4f;   // certified interp error bound ~2e-5, 5x headroom
constexpr float INV_SQRT_2PI   = 0.3989422804014327f;
// exp(-0.5*z^2) = exp2(-(z*SCALE_C)^2), SCALE_C = sqrt(0.5*log2(e))
constexpr float SCALE_C = 0.8493218002880191f;
// 128^(-0.2)  (Scott's rule factor)
constexpr float FACTOR  = 0.37892914162759955f;
constexpr float PAD_T   = 8.0f;           // grid padding in t-units (exp2(-64)~0)

// ---------------------------------------------------------------------------
// Kernel A: byte-identical to validated R6/R9 kde_prep (absmax=0 across 4
// submissions). One block per feature; fused stats + density-table build.
// ---------------------------------------------------------------------------
__global__ __launch_bounds__(G) void kde_prep(const float* __restrict__ kde,
                                              const float* __restrict__ repl,
                                              float* __restrict__ table,
                                              float4* __restrict__ const4,
                                              float* __restrict__ coefs) {
    const int f    = blockIdx.x;
    const int tid  = threadIdx.x;
    const int lane = tid & 63;
    const int wv   = tid >> 6;

    __shared__ float vbuf[N];
    __shared__ float redS[4], redSS[4], redMN[4], redMX[4];

    float v = 0.f, vmn = INFINITY, vmx = -INFINITY;
    if (tid < N) {
        v = kde[tid * F + f];
        vbuf[tid] = v;
        vmn = v;
        vmx = v;
    }
    float s  = v;
    float ss = v * v;
#pragma unroll
    for (int off = 32; off >= 1; off >>= 1) {
        s   += __shfl_xor(s, off);
        ss  += __shfl_xor(ss, off);
        vmn  = fminf(vmn, __shfl_xor(vmn, off));
        vmx  = fmaxf(vmx, __shfl_xor(vmx, off));
    }
    if (lane == 0) { redS[wv] = s; redSS[wv] = ss; redMN[wv] = vmn; redMX[wv] = vmx; }
    __syncthreads();

    const float S  = (redS[0] + redS[1]) + (redS[2] + redS[3]);
    const float SS = (redSS[0] + redSS[1]) + (redSS[2] + redSS[3]);
    const float MN = fminf(fminf(redMN[0], redMN[1]), fminf(redMN[2], redMN[3]));
    const float MX = fmaxf(fmaxf(redMX[0], redMX[1]), fmaxf(redMX[2], redMX[3]));

    const float mean  = S * (1.0f / N);
    const float var   = (SS - S * mean) * (1.0f / (N - 1));
    const float bw    = FACTOR * sqrtf(var);
    const float scale = SCALE_C / bw;
    const float coef  = INV_SQRT_2PI / bw;
    const float t0    = MN * scale - PAD_T;
    const float t1    = MX * scale + PAD_T;
    const float invht = (float)(G - 1) / (t1 - t0);
    const float ht    = 1.0f / invht;

    const float tg = fmaf((float)tid, ht, t0);
    float acc = 0.f;
#pragma unroll 8
    for (int n = 0; n < N; ++n) {
        const float a = vbuf[n] * scale;
        const float z = tg - a;
        acc += __builtin_amdgcn_exp2f(-(z * z));
    }
    table[f * G + tid] = (acc * (1.0f / N)) * coef;

    if (tid == 0) {
        const4[f] = make_float4(scale * invht, -t0 * invht, repl[f], scale);
        coefs[f]  = coef;
    }
}

// ---------------------------------------------------------------------------
// Kernel B: apply. Fast path (interp + thresholds) byte-identical to the
// validated R6/R9 kde_apply. ONLY change: the ambiguous-band refine is now
// WAVE-COOPERATIVE — ballot the rare ambiguous lanes; for each, all 64 lanes
// split the 128-term KDE sum (2 terms/lane, parallel loads) and butterfly-
// reduce, instead of one lane serializing ~4000 cycles while 63 idle.
// ---------------------------------------------------------------------------
__global__ __launch_bounds__(256) void kde_apply(const float* __restrict__ x,
                                                 const float* __restrict__ kde,
                                                 const float* __restrict__ table,
                                                 const float4* __restrict__ const4,
                                                 const float* __restrict__ coefs,
                                                 float* __restrict__ out) {
    const int e = blockIdx.x * 256 + threadIdx.x;
    const int f = e & (F - 1);

    const float  xv = x[e];
    const float4 c  = const4[f];            // {scale*invht, -t0*invht, rv, scale}
    const float  u  = fmaf(xv, c.x, c.y);

    float res    = xv;
    bool  refine = false;
    if (u >= 1.0f && u < (float)(G - 2)) {
        const int   i    = (int)u;
        const float sfr  = u - (float)i;
        const int   base = f * G + i - 1;
        const float p0 = table[base + 0];
        const float p1 = table[base + 1];
        const float p2 = table[base + 2];
        const float p3 = table[base + 3];
        const float sm1 = sfr - 1.0f, sm2 = sfr - 2.0f, sp1 = sfr + 1.0f;
        const float w0 = -sfr * sm1 * sm2 * (1.0f / 6.0f);
        const float w1 = sp1 * sm1 * sm2 * 0.5f;
        const float w2 = -sp1 * sfr * sm2 * 0.5f;
        const float w3 = sp1 * sfr * sm1 * (1.0f / 6.0f);
        const float dens = w0 * p0 + w1 * p1 + w2 * p2 + w3 * p3;

        if (dens >= PROB_THRESHOLD + MARGIN) {
            res = c.z;
        } else if (dens >= PROB_THRESHOLD - MARGIN) {
            refine = true;
        }
    }
    // (u out of range => nearest sample >= ~7.9 t-units => dens < 1e-18 => keep x)

    // ---- wave-cooperative exact refine (rare: ~5e-4 of elements) ----
    const int lane = threadIdx.x & 63;
    unsigned long long amb = __ballot(refine);
    while (amb) {
        const int src = __ffsll(amb) - 1;
        amb &= amb - 1;

        const float xj = __shfl(xv, src);
        const float sj = __shfl(c.w, src);     // scale
        const float rj = __shfl(c.z, src);     // replacement value
        const int   fj = __shfl(f, src);
        const float cj = coefs[fj];            // uniform address -> broadcast

        const float tj  = xj * sj;
        const float t2j = tj + tj;
        const float etj = __builtin_amdgcn_exp2f(-(tj * tj));

        // lane l computes terms n = 2l, 2l+1 (same factored chain as R3/R6)
        const int   n0 = lane << 1;
        const float v0 = kde[n0 * F + fj];
        const float v1 = kde[(n0 + 1) * F + fj];
        const float a0 = v0 * sj;
        const float a1 = v1 * sj;
        float part = __builtin_amdgcn_exp2f(fmaf(t2j, a0, -(a0 * a0)))
                   + __builtin_amdgcn_exp2f(fmaf(t2j, a1, -(a1 * a1)));
#pragma unroll
        for (int off = 32; off >= 1; off >>= 1) part += __shfl_xor(part, off);

        const float dens2 = ((part * etj) * (1.0f / N)) * cj;
        const float r     = (dens2 >= PROB_THRESHOLD) ? rj : xj;
        if (lane == src) res = r;
    }

    out[e] = res;
}

// ---------------------------------------------------------------------------
// Fallback (ws too small): R4's validated fused direct kernel, unchanged.
// ---------------------------------------------------------------------------
__global__ __launch_bounds__(512) void kde_mask_fused(const float* __restrict__ x,
                                                      const float* __restrict__ kde,
                                                      const float* __restrict__ repl,
                                                      float* __restrict__ out) {
    const int f  = threadIdx.x;
    const int r0 = blockIdx.x * ROWS;

    float s = 0.f, ss = 0.f;
#pragma unroll 8
    for (int n = 0; n < N; ++n) {
        const float v = kde[n * F + f];
        s += v;
        ss = fmaf(v, v, ss);
    }
    const float mean  = s * (1.0f / N);
    const float var   = (ss - s * mean) * (1.0f / (N - 1));
    const float bw    = FACTOR * sqrtf(var);
    const float scale = SCALE_C / bw;
    const float coef  = INV_SQRT_2PI / bw;

    float xv[ROWS], t2[ROWS], et[ROWS], acc[ROWS];
#pragma unroll
    for (int k = 0; k < ROWS; ++k) {
        xv[k]  = x[(r0 + k) * F + f];
        const float t = xv[k] * scale;
        t2[k]  = t + t;
        et[k]  = __builtin_amdgcn_exp2f(-(t * t));
        acc[k] = 0.f;
    }
#pragma unroll 8
    for (int n = 0; n < N; ++n) {
        const float v   = kde[n * F + f];
        const float a   = v * scale;
        const float na2 = -(a * a);
#pragma unroll
        for (int k = 0; k < ROWS; ++k) {
            acc[k] += __builtin_amdgcn_exp2f(fmaf(t2[k], a, na2));
        }
    }
    const float rv = repl[f];
#pragma unroll
    for (int k = 0; k < ROWS; ++k) {
        const float sum  = acc[k] * et[k];
        const float dens = (sum * (1.0f / N)) * coef;
        out[(r0 + k) * F + f] = (dens >= PROB_THRESHOLD) ? rv : xv[k];
    }
}

extern "C" void kernel_launch(void* const* d_in, const int* in_sizes, int n_in,
                              void* d_out, int out_size, void* d_ws, size_t ws_size,
                              hipStream_t stream) {
    const float* x    = (const float*)d_in[0];
    const float* kde  = (const float*)d_in[1];
    const float* repl = (const float*)d_in[2];
    float* out        = (float*)d_out;

    const int rows  = in_sizes[0] / F;   // B*S = 2048
    const int total = in_sizes[0];       // 1,048,576

    const size_t need = (size_t)(F * G) * sizeof(float)   // table
                      + (size_t)F * sizeof(float4)        // const4
                      + (size_t)F * sizeof(float);        // coefs
    if (ws_size >= need) {
        float*  table  = (float*)d_ws;
        float4* const4 = (float4*)(table + (size_t)F * G);  // 512KB offset, 16B-aligned
        float*  coefs  = (float*)(const4 + F);
        kde_prep<<<F, G, 0, stream>>>(kde, repl, table, const4, coefs);
        kde_apply<<<total / 256, 256, 0, stream>>>(x, kde, table, const4, coefs, out);
    } else {
        kde_mask_fused<<<rows / ROWS, 512, 0, stream>>>(x, kde, repl, out);
    }
}